// Round 1
// baseline (4590.011 us; speedup 1.0000x reference)
//
#include <hip/hip_runtime.h>
#include <math.h>

#define TILE 64
#define BKK 32
#define LDSP 68  // padded LDS row (floats): 16B-aligned rows, bank-spread

// C[bz][i,j] = sum_k A[bz][i*sAi + k*sAk] * B[bz][j*sBj + k*sBk]
// epilogue 0: C = acc + bias[j]        (bias may be null)
// epilogue 1: C = gamma[0]*acc + resid (resid indexed identically to C)
__global__ __launch_bounds__(256) void gemm_generic(
    const float* __restrict__ A, const float* __restrict__ Bm,
    const float* __restrict__ bias, const float* __restrict__ resid,
    const float* __restrict__ gammaPtr, float* __restrict__ C,
    int M, int N, int K,
    long sAi, long sAk, long bAs,
    long sBj, long sBk, long bBs,
    long sCi, long bCs, int epilogue)
{
  __shared__ __align__(16) float lds_a[BKK * LDSP];
  __shared__ __align__(16) float lds_b[BKK * LDSP];
  const int bz = blockIdx.z;
  const float* Ab = A + bAs * bz;
  const float* Bb = Bm + bBs * bz;
  const int i0 = blockIdx.y * TILE;
  const int j0 = blockIdx.x * TILE;
  const int tid = threadIdx.x;
  const int tx = tid & 15, ty = tid >> 4;
  float acc[4][4] = {};
  const bool akf = (sAk == 1);
  const bool bkf = (sBk == 1);

  for (int k0 = 0; k0 < K; k0 += BKK) {
    // stage A tile: lds_a[kk][ii]
    for (int idx = tid; idx < BKK * TILE; idx += 256) {
      int kk, ii;
      if (akf) { kk = idx & (BKK - 1); ii = idx >> 5; }   // lanes walk k (coalesced, sAk==1)
      else     { ii = idx & (TILE - 1); kk = idx >> 6; }  // lanes walk i (coalesced, sAi==1)
      int gi = i0 + ii, gk = k0 + kk;
      float v = 0.f;
      if (gi < M && gk < K) v = Ab[(long)gi * sAi + (long)gk * sAk];
      lds_a[kk * LDSP + ii] = v;
    }
    // stage B tile: lds_b[kk][jj]
    for (int idx = tid; idx < BKK * TILE; idx += 256) {
      int kk, jj;
      if (bkf) { kk = idx & (BKK - 1); jj = idx >> 5; }
      else     { jj = idx & (TILE - 1); kk = idx >> 6; }
      int gj = j0 + jj, gk = k0 + kk;
      float v = 0.f;
      if (gj < N && gk < K) v = Bb[(long)gj * sBj + (long)gk * sBk];
      lds_b[kk * LDSP + jj] = v;
    }
    __syncthreads();
    #pragma unroll
    for (int kk = 0; kk < BKK; ++kk) {
      const float4 a4 = *reinterpret_cast<const float4*>(&lds_a[kk * LDSP + ty * 4]);
      const float4 b4 = *reinterpret_cast<const float4*>(&lds_b[kk * LDSP + tx * 4]);
      const float av[4] = {a4.x, a4.y, a4.z, a4.w};
      const float bv[4] = {b4.x, b4.y, b4.z, b4.w};
      #pragma unroll
      for (int a = 0; a < 4; ++a)
        #pragma unroll
        for (int b = 0; b < 4; ++b)
          acc[a][b] = fmaf(av[a], bv[b], acc[a][b]);
    }
    __syncthreads();
  }

  const float g = (epilogue == 1) ? gammaPtr[0] : 1.f;
  for (int a = 0; a < 4; ++a) {
    int gi = i0 + ty * 4 + a;
    if (gi >= M) continue;
    for (int b = 0; b < 4; ++b) {
      int gj = j0 + tx * 4 + b;
      if (gj >= N) continue;
      long ci = bCs * bz + (long)gi * sCi + gj;
      float v = acc[a][b];
      if (epilogue == 0) {
        if (bias) v += bias[gj];
        C[ci] = v;
      } else {
        C[ci] = g * v + resid[ci];
      }
    }
  }
}

// bf[c] = sum_e Wks[c,e]*bk[e] + bks[c]   (c < 96)
__global__ void fuse_bias(const float* __restrict__ Wks, const float* __restrict__ bk,
                          const float* __restrict__ bks, float* __restrict__ bf) {
  int c = blockIdx.x * blockDim.x + threadIdx.x;
  if (c >= 96) return;
  float s = bks[c];
  for (int e = 0; e < 96; ++e) s += Wks[c * 96 + e] * bk[e];
  bf[c] = s;
}

// in-place row softmax, rows of length 197, one wave per row
__global__ __launch_bounds__(256) void softmax_rows(float* __restrict__ A, int nrows) {
  int row = blockIdx.x * 4 + (threadIdx.x >> 6);
  int lane = threadIdx.x & 63;
  if (row >= nrows) return;
  float* p = A + (long)row * 197;
  float v[4];
  float mx = -INFINITY;
  #pragma unroll
  for (int j = 0; j < 4; ++j) {
    int m = lane + j * 64;
    v[j] = (m < 197) ? p[m] : -INFINITY;
    mx = fmaxf(mx, v[j]);
  }
  #pragma unroll
  for (int off = 32; off > 0; off >>= 1) mx = fmaxf(mx, __shfl_xor(mx, off));
  float s = 0.f;
  #pragma unroll
  for (int j = 0; j < 4; ++j) {
    int m = lane + j * 64;
    if (m < 197) { v[j] = __expf(v[j] - mx); s += v[j]; }
  }
  #pragma unroll
  for (int off = 32; off > 0; off >>= 1) s += __shfl_xor(s, off);
  float inv = 1.f / s;
  #pragma unroll
  for (int j = 0; j < 4; ++j) {
    int m = lane + j * 64;
    if (m < 197) p[m] = v[j] * inv;
  }
}

extern "C" void kernel_launch(void* const* d_in, const int* in_sizes, int n_in,
                              void* d_out, int out_size, void* d_ws, size_t ws_size,
                              hipStream_t stream) {
  const float* x   = (const float*)d_in[0];
  const float* y   = (const float*)d_in[1];
  const float* Wk1 = (const float*)d_in[2];
  const float* bk1 = (const float*)d_in[3];
  const float* Wk2 = (const float*)d_in[4];
  const float* bk2 = (const float*)d_in[5];
  const float* Wks = (const float*)d_in[6];
  const float* bks = (const float*)d_in[7];
  const float* Wl1 = (const float*)d_in[8];
  const float* bl1 = (const float*)d_in[9];
  const float* Wl2 = (const float*)d_in[10];
  const float* bl2 = (const float*)d_in[11];
  const float* Wv1 = (const float*)d_in[12];
  const float* bv1 = (const float*)d_in[13];
  const float* Wv2 = (const float*)d_in[14];
  const float* bv2 = (const float*)d_in[15];
  const float* gamma1 = (const float*)d_in[16];
  const float* gamma2 = (const float*)d_in[17];
  float* out = (float*)d_out;
  float* ws  = (float*)d_ws;

  const int B = 256, L = 197, D = 768, DK = 96;
  const long LD  = (long)L * D;   // 151296
  const long LDK = (long)L * DK;  // 18912
  const long LL  = (long)L * L;   // 38809

  // chunk the batch so workspace fits
  int Bc = 256;
  auto need = [&](int bc) -> size_t {
    return ((size_t)(2 * 73728 + 256) + (size_t)bc * (2 * LDK + 3 * LL + LD)) * 4;
  };
  while (Bc > 4 && need(Bc) > ws_size) Bc >>= 1;

  float* Wf1 = ws;
  float* Wf2 = Wf1 + 73728;
  float* bf1 = Wf2 + 73728;
  float* bf2 = bf1 + 128;
  float* k1  = bf2 + 128;
  float* k2  = k1 + (long)Bc * LDK;
  float* energy = k2 + (long)Bc * LDK;
  float* att1   = energy + (long)Bc * LL;
  float* att2   = att1 + (long)Bc * LL;   // contiguous with att1 (softmax covers both)
  float* vbuf   = att2 + (long)Bc * LL;

  dim3 blk(256);

  // Wf = Wks @ Wk : M=96, N=768, K=96
  gemm_generic<<<dim3(12, 2, 1), blk, 0, stream>>>(Wks, Wk1, nullptr, nullptr, nullptr, Wf1,
      96, 768, 96, 96, 1, 0, 1, 768, 0, 768, 0, 0);
  gemm_generic<<<dim3(12, 2, 1), blk, 0, stream>>>(Wks, Wk2, nullptr, nullptr, nullptr, Wf2,
      96, 768, 96, 96, 1, 0, 1, 768, 0, 768, 0, 0);
  fuse_bias<<<1, 128, 0, stream>>>(Wks, bk1, bks, bf1);
  fuse_bias<<<1, 128, 0, stream>>>(Wks, bk2, bks, bf2);

  for (int c0 = 0; c0 < B; c0 += Bc) {
    const float* xc = x + (long)c0 * LD;
    const float* yc = y + (long)c0 * LD;
    const int Mr = Bc * L;
    const int gym = (Mr + TILE - 1) / TILE;

    // k1 = xc @ Wf1^T + bf1 ; k2 = yc @ Wf2^T + bf2   (M=Bc*L, N=96, K=768)
    gemm_generic<<<dim3(2, gym, 1), blk, 0, stream>>>(xc, Wf1, bf1, nullptr, nullptr, k1,
        Mr, 96, 768, 768, 1, 0, 768, 1, 0, 96, 0, 0);
    gemm_generic<<<dim3(2, gym, 1), blk, 0, stream>>>(yc, Wf2, bf2, nullptr, nullptr, k2,
        Mr, 96, 768, 768, 1, 0, 768, 1, 0, 96, 0, 0);

    // energy[b,l,m] = sum_c k1[b, c*L+l] * k2[b, c*L+m]   (M=N=197, K=96)
    gemm_generic<<<dim3(4, 4, Bc), blk, 0, stream>>>(k1, k2, nullptr, nullptr, nullptr, energy,
        197, 197, 96, 1, 197, LDK, 1, 197, LDK, 197, LL, 0);

    // att1 logits = energy @ Wl1^T + bl1
    gemm_generic<<<dim3(4, 4, Bc), blk, 0, stream>>>(energy, Wl1, bl1, nullptr, nullptr, att1,
        197, 197, 197, 197, 1, LL, 197, 1, 0, 197, LL, 0);
    // att2 logits = energy^T @ Wl2^T + bl2
    gemm_generic<<<dim3(4, 4, Bc), blk, 0, stream>>>(energy, Wl2, bl2, nullptr, nullptr, att2,
        197, 197, 197, 1, 197, LL, 197, 1, 0, 197, LL, 0);

    // softmax over both att buffers (contiguous rows)
    {
      int nrows = 2 * Bc * 197;
      softmax_rows<<<dim3((nrows + 3) / 4), blk, 0, stream>>>(att1, nrows);
    }

    // v2 = yc @ Wv2^T + bv2   (M=Bc*L, N=768, K=768)
    gemm_generic<<<dim3(12, gym, 1), blk, 0, stream>>>(yc, Wv2, bv2, nullptr, nullptr, vbuf,
        Mr, 768, 768, 768, 1, 0, 768, 1, 0, 768, 0, 0);
    // out_x[b].flat[d*197+m] = gamma1 * sum_l v2[b,l,d]*att1[b,l,m] + xc[b].flat
    gemm_generic<<<dim3(4, 12, Bc), blk, 0, stream>>>(vbuf, att1, nullptr, xc, gamma1,
        out + (long)c0 * LD,
        768, 197, 197, 1, 768, LD, 1, 197, LL, 197, LD, 1);

    // v1 = xc @ Wv1^T + bv1
    gemm_generic<<<dim3(12, gym, 1), blk, 0, stream>>>(xc, Wv1, bv1, nullptr, nullptr, vbuf,
        Mr, 768, 768, 768, 1, 0, 768, 1, 0, 768, 0, 0);
    // out_y
    gemm_generic<<<dim3(4, 12, Bc), blk, 0, stream>>>(vbuf, att2, nullptr, yc, gamma2,
        out + (long)B * LD + (long)c0 * LD,
        768, 197, 197, 1, 768, LD, 1, 197, LL, 197, LD, 1);
  }
}

// Round 2
// 1324.281 us; speedup vs baseline: 3.4660x; 3.4660x over previous
//
#include <hip/hip_runtime.h>
#include <math.h>

typedef unsigned short ushort;
typedef __attribute__((ext_vector_type(8))) short short8;
typedef __attribute__((ext_vector_type(8))) unsigned short ushort8;
typedef __attribute__((ext_vector_type(4))) float f32x4;
typedef unsigned int u32;

__device__ __forceinline__ ushort f2bf(float f) {
  u32 u = __float_as_uint(f);
  return (ushort)((u + 0x7FFF + ((u >> 16) & 1)) >> 16);
}

__device__ __forceinline__ void gload16(const void* g, void* l) {
  __builtin_amdgcn_global_load_lds(
      (const __attribute__((address_space(1))) u32*)g,
      (__attribute__((address_space(3))) u32*)l, 16, 0, 0);
}

// ---------------- fp32 VALU GEMM (energy + small weight-fuse GEMMs) ----------
#define TILE 64
#define BKK 32
#define LDSP 68
__global__ __launch_bounds__(256) void gemm_generic(
    const float* __restrict__ A, const float* __restrict__ Bm,
    float* __restrict__ C,
    int M, int N, int K,
    long sAi, long sAk, long bAs,
    long sBj, long sBk, long bBs,
    long sCi, long bCs)
{
  __shared__ __align__(16) float lds_a[BKK * LDSP];
  __shared__ __align__(16) float lds_b[BKK * LDSP];
  const int bz = blockIdx.z;
  const float* Ab = A + bAs * bz;
  const float* Bb = Bm + bBs * bz;
  const int i0 = blockIdx.y * TILE;
  const int j0 = blockIdx.x * TILE;
  const int tid = threadIdx.x;
  const int tx = tid & 15, ty = tid >> 4;
  float acc[4][4] = {};
  const bool akf = (sAk == 1);
  const bool bkf = (sBk == 1);

  for (int k0 = 0; k0 < K; k0 += BKK) {
    for (int idx = tid; idx < BKK * TILE; idx += 256) {
      int kk, ii;
      if (akf) { kk = idx & (BKK - 1); ii = idx >> 5; }
      else     { ii = idx & (TILE - 1); kk = idx >> 6; }
      int gi = i0 + ii, gk = k0 + kk;
      float v = 0.f;
      if (gi < M && gk < K) v = Ab[(long)gi * sAi + (long)gk * sAk];
      lds_a[kk * LDSP + ii] = v;
    }
    for (int idx = tid; idx < BKK * TILE; idx += 256) {
      int kk, jj;
      if (bkf) { kk = idx & (BKK - 1); jj = idx >> 5; }
      else     { jj = idx & (TILE - 1); kk = idx >> 6; }
      int gj = j0 + jj, gk = k0 + kk;
      float v = 0.f;
      if (gj < N && gk < K) v = Bb[(long)gj * sBj + (long)gk * sBk];
      lds_b[kk * LDSP + jj] = v;
    }
    __syncthreads();
    #pragma unroll
    for (int kk = 0; kk < BKK; ++kk) {
      const float4 a4 = *reinterpret_cast<const float4*>(&lds_a[kk * LDSP + ty * 4]);
      const float4 b4 = *reinterpret_cast<const float4*>(&lds_b[kk * LDSP + tx * 4]);
      const float av[4] = {a4.x, a4.y, a4.z, a4.w};
      const float bv[4] = {b4.x, b4.y, b4.z, b4.w};
      #pragma unroll
      for (int a = 0; a < 4; ++a)
        #pragma unroll
        for (int b = 0; b < 4; ++b)
          acc[a][b] = fmaf(av[a], bv[b], acc[a][b]);
    }
    __syncthreads();
  }
  for (int a = 0; a < 4; ++a) {
    int gi = i0 + ty * 4 + a;
    if (gi >= M) continue;
    for (int b = 0; b < 4; ++b) {
      int gj = j0 + tx * 4 + b;
      if (gj >= N) continue;
      C[bCs * bz + (long)gi * sCi + gj] = acc[a][b];
    }
  }
}

// ---------------- bf16 MFMA GEMM ---------------------------------------------
// C[bz][i,j] = sum_k A[bz][i*sAi + k] * B[bz][j*sBj + k]   (k-contiguous, K%64==0)
// mode 0: f32 out, + bias[col] (optional)
// mode 1: bf16 out, + bias[row]; zero-fill cols [N, Npad)
// mode 2: f32 out, + bias[row]
// mode 3: f32 out, gamma[0]*acc + resid[same index]
__global__ __launch_bounds__(256) void mfma_gemm(
    const ushort* __restrict__ A, const ushort* __restrict__ Bm,
    const float* __restrict__ bias, const float* __restrict__ resid,
    const float* __restrict__ gammaPtr, void* __restrict__ C,
    int M, int N, int K,
    long sAi, long bAs, long sBj, long bBs,
    long sCi, long bCs, int Npad, int mode)
{
  __shared__ ushort As[128 * 64];
  __shared__ ushort Bs[128 * 64];
  const int bz = blockIdx.z;
  const ushort* Ab = A + bAs * bz;
  const ushort* Bb = Bm + bBs * bz;
  const int i0 = blockIdx.y * 128;
  const int j0 = blockIdx.x * 128;
  const int tid = threadIdx.x;
  const int wave = tid >> 6, lane = tid & 63;
  const int wm = wave >> 1, wn = wave & 1;      // 2x2 wave grid, 64x64 per wave
  const int col16 = lane & 15, krow = lane >> 4;

  f32x4 acc[4][4] = {};

  for (int k0 = 0; k0 < K; k0 += 64) {
    // stage A tile [128 rows][64 k] bf16, XOR-swizzled 16B slots
    #pragma unroll
    for (int it = 0; it < 4; ++it) {
      int chunk = it * 256 + wave * 64 + lane;   // 0..1023
      int row = chunk >> 3, s = chunk & 7;
      int kc = s ^ (row & 7);                    // pre-swizzled global source
      int gi = i0 + row; if (gi >= M) gi = M - 1;
      gload16(Ab + (long)gi * sAi + k0 + kc * 8, &As[chunk * 8]);
    }
    #pragma unroll
    for (int it = 0; it < 4; ++it) {
      int chunk = it * 256 + wave * 64 + lane;
      int row = chunk >> 3, s = chunk & 7;
      int kc = s ^ (row & 7);
      int gj = j0 + row; if (gj >= N) gj = N - 1;
      gload16(Bb + (long)gj * sBj + k0 + kc * 8, &Bs[chunk * 8]);
    }
    __syncthreads();   // compiler drains vmcnt before barrier -> data ready
    #pragma unroll
    for (int ks = 0; ks < 2; ++ks) {
      short8 af[4], bfr[4];
      #pragma unroll
      for (int mi = 0; mi < 4; ++mi) {
        int row = wm * 64 + mi * 16 + col16;
        int slot = (ks * 4 + krow) ^ (row & 7);
        af[mi] = *(const short8*)&As[row * 64 + slot * 8];
      }
      #pragma unroll
      for (int nj = 0; nj < 4; ++nj) {
        int row = wn * 64 + nj * 16 + col16;
        int slot = (ks * 4 + krow) ^ (row & 7);
        bfr[nj] = *(const short8*)&Bs[row * 64 + slot * 8];
      }
      #pragma unroll
      for (int mi = 0; mi < 4; ++mi)
        #pragma unroll
        for (int nj = 0; nj < 4; ++nj)
          acc[mi][nj] = __builtin_amdgcn_mfma_f32_16x16x32_bf16(
              af[mi], bfr[nj], acc[mi][nj], 0, 0, 0);
    }
    __syncthreads();   // compute done before next stage overwrites LDS
  }

  const int r0 = (lane >> 4) * 4;
  const float g = (mode == 3) ? gammaPtr[0] : 0.f;
  #pragma unroll
  for (int mi = 0; mi < 4; ++mi) {
    int gi0 = i0 + wm * 64 + mi * 16 + r0;
    #pragma unroll
    for (int nj = 0; nj < 4; ++nj) {
      int gj = j0 + wn * 64 + nj * 16 + col16;
      f32x4 a = acc[mi][nj];
      #pragma unroll
      for (int r = 0; r < 4; ++r) {
        int gi = gi0 + r;
        if (gi >= M) continue;
        long ci = bCs * bz + (long)gi * sCi + gj;
        if (mode == 0) {
          if (gj < N) {
            float v = a[r] + (bias ? bias[gj] : 0.f);
            ((float*)C)[ci] = v;
          }
        } else if (mode == 1) {
          if (gj < Npad) {
            ushort o = 0;
            if (gj < N) o = f2bf(a[r] + bias[gi]);
            ((ushort*)C)[ci] = o;
          }
        } else if (mode == 2) {
          if (gj < N) ((float*)C)[ci] = a[r] + bias[gi];
        } else {
          if (gj < N) ((float*)C)[ci] = g * a[r] + resid[ci];
        }
      }
    }
  }
}

// ---------------- small helpers ----------------------------------------------
__global__ void fuse_bias(const float* __restrict__ Wks, const float* __restrict__ bk,
                          const float* __restrict__ bks, float* __restrict__ bf) {
  int c = blockIdx.x * blockDim.x + threadIdx.x;
  if (c >= 96) return;
  float s = bks[c];
  for (int e = 0; e < 96; ++e) s += Wks[c * 96 + e] * bk[e];
  bf[c] = s;
}

__global__ __launch_bounds__(256) void conv_plain(const float* __restrict__ s,
                                                  ushort* __restrict__ d, long n) {
  long i = (long)blockIdx.x * blockDim.x + threadIdx.x;
  long stride = (long)gridDim.x * blockDim.x;
  for (; i < n; i += stride) d[i] = f2bf(s[i]);
}

// rows x cols f32 -> rows x 256 bf16, zero pad cols [cols,256)
__global__ __launch_bounds__(256) void conv_pad256(const float* __restrict__ s,
                                                   ushort* __restrict__ d,
                                                   int rows, int cols) {
  long i = (long)blockIdx.x * blockDim.x + threadIdx.x;
  long n = (long)rows * 256;
  long stride = (long)gridDim.x * blockDim.x;
  for (; i < n; i += stride) {
    int r = (int)(i >> 8), c = (int)(i & 255);
    d[i] = (c < cols) ? f2bf(s[(long)r * cols + c]) : (ushort)0;
  }
}

// vectorized f32 -> bf16, n8 = n/8
__global__ __launch_bounds__(256) void conv_bf16x8(const float* __restrict__ s,
                                                   ushort* __restrict__ d, long n8) {
  long i = (long)blockIdx.x * blockDim.x + threadIdx.x;
  long stride = (long)gridDim.x * blockDim.x;
  for (; i < n8; i += stride) {
    float4 a = ((const float4*)s)[2 * i];
    float4 b = ((const float4*)s)[2 * i + 1];
    ushort8 o;
    o[0] = f2bf(a.x); o[1] = f2bf(a.y); o[2] = f2bf(a.z); o[3] = f2bf(a.w);
    o[4] = f2bf(b.x); o[5] = f2bf(b.y); o[6] = f2bf(b.z); o[7] = f2bf(b.w);
    *(ushort8*)&d[i * 8] = o;
  }
}

// E [197][197] f32 -> Eb [197][256] bf16 (pad 0) and ETb [197][256] bf16 (pad 0)
__global__ __launch_bounds__(256) void convE(const float* __restrict__ E,
                                             ushort* __restrict__ Ebuf,
                                             ushort* __restrict__ ETbuf) {
  __shared__ float tile[32][33];
  int b = blockIdx.z;
  const float* Es = E + (long)b * 38809;
  ushort* eb = Ebuf + (long)b * 50432;
  ushort* et = ETbuf + (long)b * 50432;
  int l0 = blockIdx.y * 32, m0 = blockIdx.x * 32;
  int tx = threadIdx.x & 31, ty = threadIdx.x >> 5;   // 32 x 8
  for (int r = ty; r < 32; r += 8) {
    int l = l0 + r, m = m0 + tx;
    tile[r][tx] = (l < 197 && m < 197) ? Es[(long)l * 197 + m] : 0.f;
  }
  __syncthreads();
  for (int r = ty; r < 32; r += 8) {
    int l = l0 + r, m = m0 + tx;
    if (l < 197 && m < 256) eb[(long)l * 256 + m] = f2bf(tile[r][tx]);
  }
  for (int r = ty; r < 32; r += 8) {
    int m = m0 + r, l = l0 + tx;
    if (m < 197 && l < 256) et[(long)m * 256 + l] = f2bf(tile[tx][r]);
  }
}

// column softmax: t [197 rows][256 stride] f32, softmax over rows per col l<197,
// out a bf16 same layout; cols [197,256) -> 0
__global__ __launch_bounds__(256) void softmax_cols(const float* __restrict__ t1,
                                                    const float* __restrict__ t2,
                                                    ushort* __restrict__ a1,
                                                    ushort* __restrict__ a2) {
  int bid = blockIdx.x;
  int b = bid >> 1;
  const float* t = (bid & 1) ? t2 : t1;
  ushort* a = (bid & 1) ? a2 : a1;
  t += (long)b * 50432;
  a += (long)b * 50432;
  int l = threadIdx.x;
  if (l >= 197) {
    for (int m = 0; m < 197; ++m) a[(long)m * 256 + l] = 0;
    return;
  }
  float mx = -INFINITY;
  for (int m = 0; m < 197; ++m) mx = fmaxf(mx, t[(long)m * 256 + l]);
  float s = 0.f;
  for (int m = 0; m < 197; ++m) s += __expf(t[(long)m * 256 + l] - mx);
  float inv = 1.f / s;
  for (int m = 0; m < 197; ++m)
    a[(long)m * 256 + l] = f2bf(__expf(t[(long)m * 256 + l] - mx) * inv);
}

// ---------------- launcher ---------------------------------------------------
extern "C" void kernel_launch(void* const* d_in, const int* in_sizes, int n_in,
                              void* d_out, int out_size, void* d_ws, size_t ws_size,
                              hipStream_t stream) {
  const float* x   = (const float*)d_in[0];
  const float* y   = (const float*)d_in[1];
  const float* Wk1 = (const float*)d_in[2];
  const float* bk1 = (const float*)d_in[3];
  const float* Wk2 = (const float*)d_in[4];
  const float* bk2 = (const float*)d_in[5];
  const float* Wks = (const float*)d_in[6];
  const float* bks = (const float*)d_in[7];
  const float* Wl1 = (const float*)d_in[8];
  const float* bl1 = (const float*)d_in[9];
  const float* Wl2 = (const float*)d_in[10];
  const float* bl2 = (const float*)d_in[11];
  const float* Wv1 = (const float*)d_in[12];
  const float* bv1 = (const float*)d_in[13];
  const float* Wv2 = (const float*)d_in[14];
  const float* bv2 = (const float*)d_in[15];
  const float* gamma1 = (const float*)d_in[16];
  const float* gamma2 = (const float*)d_in[17];
  float* out = (float*)d_out;

  const int B = 256, L = 197, D = 768;
  const long LD  = (long)L * D;    // 151296
  const long LDK = (long)L * 96;   // 18912
  const long LL  = (long)L * L;    // 38809

  // ---- workspace budget / chunking ----
  const size_t staticBytes = 589824 + 1024 + 2359296 + 294912 + 201728;
  const size_t perB = 605184 + 151296 + 155264 + 201728 + 403456 + 201728 + 393216;
  int Bc = 256;
  while (Bc > 4 && staticBytes + (size_t)Bc * perB > ws_size) Bc >>= 1;

  char* p = (char*)d_ws;
  auto carve = [&](size_t bytes) { char* r = p; p += bytes; return r; };
  float*  Wf1   = (float*)carve(73728 * 4);
  float*  Wf2   = (float*)carve(73728 * 4);
  float*  bf1   = (float*)carve(512);
  float*  bf2   = (float*)carve(512);
  ushort* Wv1b  = (ushort*)carve(589824 * 2);
  ushort* Wv2b  = (ushort*)carve(589824 * 2);
  ushort* Wf1b  = (ushort*)carve(73728 * 2);
  ushort* Wf2b  = (ushort*)carve(73728 * 2);
  ushort* Wl1b  = (ushort*)carve(50432 * 2);
  ushort* Wl2b  = (ushort*)carve(50432 * 2);
  ushort* xb    = (ushort*)carve((size_t)Bc * LD * 2);
  ushort* yb    = (ushort*)carve((size_t)Bc * LD * 2);
  float*  k1    = (float*)carve((size_t)Bc * LDK * 4);
  float*  k2    = (float*)carve((size_t)Bc * LDK * 4);
  float*  E     = (float*)carve((size_t)Bc * 155264);
  ushort* Ebuf  = (ushort*)carve((size_t)Bc * 50432 * 2);
  ushort* ETbuf = (ushort*)carve((size_t)Bc * 50432 * 2);
  float*  t1    = (float*)carve((size_t)Bc * 50432 * 4);
  float*  t2    = (float*)carve((size_t)Bc * 50432 * 4);
  ushort* a1    = (ushort*)carve((size_t)Bc * 50432 * 2);
  ushort* a2    = (ushort*)carve((size_t)Bc * 50432 * 2);
  ushort* vT    = (ushort*)carve((size_t)Bc * 196608 * 2);

  dim3 blk(256);

  // ---- static prep (weights) ----
  gemm_generic<<<dim3(12, 2, 1), blk, 0, stream>>>(Wks, Wk1, Wf1,
      96, 768, 96, 96, 1, 0, 1, 768, 0, 768, 0);
  gemm_generic<<<dim3(12, 2, 1), blk, 0, stream>>>(Wks, Wk2, Wf2,
      96, 768, 96, 96, 1, 0, 1, 768, 0, 768, 0);
  fuse_bias<<<1, 128, 0, stream>>>(Wks, bk1, bks, bf1);
  fuse_bias<<<1, 128, 0, stream>>>(Wks, bk2, bks, bf2);
  conv_plain<<<dim3(72), blk, 0, stream>>>(Wf1, Wf1b, 73728);
  conv_plain<<<dim3(72), blk, 0, stream>>>(Wf2, Wf2b, 73728);
  conv_plain<<<dim3(576), blk, 0, stream>>>(Wv1, Wv1b, 589824);
  conv_plain<<<dim3(576), blk, 0, stream>>>(Wv2, Wv2b, 589824);
  conv_pad256<<<dim3(200), blk, 0, stream>>>(Wl1, Wl1b, 197, 197);
  conv_pad256<<<dim3(200), blk, 0, stream>>>(Wl2, Wl2b, 197, 197);

  for (int c0 = 0; c0 < B; c0 += Bc) {
    const float* xc = x + (long)c0 * LD;
    const float* yc = y + (long)c0 * LD;
    const int Mr = Bc * L;
    const int gym = (Mr + 127) / 128;

    conv_bf16x8<<<dim3(2048), blk, 0, stream>>>(xc, xb, (long)Bc * LD / 8);
    conv_bf16x8<<<dim3(2048), blk, 0, stream>>>(yc, yb, (long)Bc * LD / 8);

    // k1 = xb @ Wf1b^T + bf1 -> f32 [Mr][96]
    mfma_gemm<<<dim3(1, gym, 1), blk, 0, stream>>>(xb, Wf1b, bf1, nullptr, nullptr, k1,
        Mr, 96, 768, 768, 0, 768, 0, 96, 0, 96, 0);
    mfma_gemm<<<dim3(1, gym, 1), blk, 0, stream>>>(yb, Wf2b, bf2, nullptr, nullptr, k2,
        Mr, 96, 768, 768, 0, 768, 0, 96, 0, 96, 0);

    // energy (fp32 VALU): E[b][l][m] = sum_c k1f[c*197+l] * k2f[c*197+m]
    gemm_generic<<<dim3(4, 4, Bc), blk, 0, stream>>>(k1, k2, E,
        197, 197, 96, 1, 197, LDK, 1, 197, LDK, 197, LL);

    convE<<<dim3(8, 8, Bc), blk, 0, stream>>>(E, Ebuf, ETbuf);

    // t1[m][l] = sum_m' Wl1[m][m'] * E[l][m'] + bl1[m]
    mfma_gemm<<<dim3(2, 2, Bc), blk, 0, stream>>>(Wl1b, Ebuf, bl1, nullptr, nullptr, t1,
        197, 197, 256, 256, 0, 256, 50432, 256, 50432, 197, 2);
    // t2[n][m] = sum_l Wl2[n][l] * ET[m][l] + bl2[n]
    mfma_gemm<<<dim3(2, 2, Bc), blk, 0, stream>>>(Wl2b, ETbuf, bl2, nullptr, nullptr, t2,
        197, 197, 256, 256, 0, 256, 50432, 256, 50432, 197, 2);

    softmax_cols<<<dim3(2 * Bc), blk, 0, stream>>>(t1, t2, a1, a2);

    // vT = (y @ Wv2^T + bv2)^T : [768][256-padded] bf16 per b
    mfma_gemm<<<dim3(2, 6, Bc), blk, 0, stream>>>(Wv2b, yb, bv2, nullptr, nullptr, vT,
        768, 197, 768, 768, 0, 768, LD, 256, 196608, 256, 1);
    // out_x = gamma1 * vT @ a1^T + x
    mfma_gemm<<<dim3(2, 6, Bc), blk, 0, stream>>>(vT, a1, nullptr, xc, gamma1,
        out + (long)c0 * LD,
        768, 197, 256, 256, 196608, 256, 50432, 197, LD, 197, 3);

    // vT = (x @ Wv1^T + bv1)^T
    mfma_gemm<<<dim3(2, 6, Bc), blk, 0, stream>>>(Wv1b, xb, bv1, nullptr, nullptr, vT,
        768, 197, 768, 768, 0, 768, LD, 256, 196608, 256, 1);
    // out_y = gamma2 * vT @ a2^T + y
    mfma_gemm<<<dim3(2, 6, Bc), blk, 0, stream>>>(vT, a2, nullptr, yc, gamma2,
        out + (long)B * LD + (long)c0 * LD,
        768, 197, 256, 256, 196608, 256, 50432, 197, LD, 197, 3);
  }
}

// Round 3
// 1060.065 us; speedup vs baseline: 4.3299x; 1.2492x over previous
//
#include <hip/hip_runtime.h>
#include <math.h>

typedef unsigned short ushort;
typedef __attribute__((ext_vector_type(8))) short short8;
typedef __attribute__((ext_vector_type(8))) unsigned short ushort8;
typedef __attribute__((ext_vector_type(4))) float f32x4;
typedef unsigned int u32;

__device__ __forceinline__ ushort f2bf(float f) {
  u32 u = __float_as_uint(f);
  return (ushort)((u + 0x7FFF + ((u >> 16) & 1)) >> 16);
}

__device__ __forceinline__ void gload16(const void* g, void* l) {
  __builtin_amdgcn_global_load_lds(
      (const __attribute__((address_space(1))) u32*)g,
      (__attribute__((address_space(3))) u32*)l, 16, 0, 0);
}

// ---------------- fp32 VALU GEMM (energy + small weight-fuse GEMMs) ----------
#define TILE 64
#define BKK 32
#define LDSP 68
__global__ __launch_bounds__(256) void gemm_generic(
    const float* __restrict__ A, const float* __restrict__ Bm,
    float* __restrict__ C,
    int M, int N, int K,
    long sAi, long sAk, long bAs,
    long sBj, long sBk, long bBs,
    long sCi, long bCs)
{
  __shared__ __align__(16) float lds_a[BKK * LDSP];
  __shared__ __align__(16) float lds_b[BKK * LDSP];
  const int bz = blockIdx.z;
  const float* Ab = A + bAs * bz;
  const float* Bb = Bm + bBs * bz;
  const int i0 = blockIdx.y * TILE;
  const int j0 = blockIdx.x * TILE;
  const int tid = threadIdx.x;
  const int tx = tid & 15, ty = tid >> 4;
  float acc[4][4] = {};
  const bool akf = (sAk == 1);
  const bool bkf = (sBk == 1);

  for (int k0 = 0; k0 < K; k0 += BKK) {
    for (int idx = tid; idx < BKK * TILE; idx += 256) {
      int kk, ii;
      if (akf) { kk = idx & (BKK - 1); ii = idx >> 5; }
      else     { ii = idx & (TILE - 1); kk = idx >> 6; }
      int gi = i0 + ii, gk = k0 + kk;
      float v = 0.f;
      if (gi < M && gk < K) v = Ab[(long)gi * sAi + (long)gk * sAk];
      lds_a[kk * LDSP + ii] = v;
    }
    for (int idx = tid; idx < BKK * TILE; idx += 256) {
      int kk, jj;
      if (bkf) { kk = idx & (BKK - 1); jj = idx >> 5; }
      else     { jj = idx & (TILE - 1); kk = idx >> 6; }
      int gj = j0 + jj, gk = k0 + kk;
      float v = 0.f;
      if (gj < N && gk < K) v = Bb[(long)gj * sBj + (long)gk * sBk];
      lds_b[kk * LDSP + jj] = v;
    }
    __syncthreads();
    #pragma unroll
    for (int kk = 0; kk < BKK; ++kk) {
      const float4 a4 = *reinterpret_cast<const float4*>(&lds_a[kk * LDSP + ty * 4]);
      const float4 b4 = *reinterpret_cast<const float4*>(&lds_b[kk * LDSP + tx * 4]);
      const float av[4] = {a4.x, a4.y, a4.z, a4.w};
      const float bv[4] = {b4.x, b4.y, b4.z, b4.w};
      #pragma unroll
      for (int a = 0; a < 4; ++a)
        #pragma unroll
        for (int b = 0; b < 4; ++b)
          acc[a][b] = fmaf(av[a], bv[b], acc[a][b]);
    }
    __syncthreads();
  }
  for (int a = 0; a < 4; ++a) {
    int gi = i0 + ty * 4 + a;
    if (gi >= M) continue;
    for (int b = 0; b < 4; ++b) {
      int gj = j0 + tx * 4 + b;
      if (gj >= N) continue;
      C[bCs * bz + (long)gi * sCi + gj] = acc[a][b];
    }
  }
}

// ---------------- bf16 MFMA GEMM, 128x128 tile (k1/k2, t1/t2) ----------------
// C[bz][i,j] = sum_k A[bz][i*sAi + k] * B[bz][j*sBj + k]   (k-contiguous, K%64==0)
// mode 0: f32 out, + bias[col] (optional)
// mode 2: f32 out, + bias[row]
__global__ __launch_bounds__(256) void mfma_gemm(
    const ushort* __restrict__ A, const ushort* __restrict__ Bm,
    const float* __restrict__ bias, void* __restrict__ C,
    int M, int N, int K,
    long sAi, long bAs, long sBj, long bBs,
    long sCi, long bCs, int mode)
{
  __shared__ ushort As[128 * 64];
  __shared__ ushort Bs[128 * 64];
  const int bz = blockIdx.z;
  const ushort* Ab = A + bAs * bz;
  const ushort* Bb = Bm + bBs * bz;
  const int i0 = blockIdx.y * 128;
  const int j0 = blockIdx.x * 128;
  const int tid = threadIdx.x;
  const int wave = tid >> 6, lane = tid & 63;
  const int wm = wave >> 1, wn = wave & 1;
  const int col16 = lane & 15, krow = lane >> 4;

  f32x4 acc[4][4] = {};

  for (int k0 = 0; k0 < K; k0 += 64) {
    #pragma unroll
    for (int it = 0; it < 4; ++it) {
      int chunk = it * 256 + wave * 64 + lane;
      int row = chunk >> 3, s = chunk & 7;
      int kc = s ^ (row & 7);
      int gi = i0 + row; if (gi >= M) gi = M - 1;
      gload16(Ab + (long)gi * sAi + k0 + kc * 8, &As[chunk * 8]);
    }
    #pragma unroll
    for (int it = 0; it < 4; ++it) {
      int chunk = it * 256 + wave * 64 + lane;
      int row = chunk >> 3, s = chunk & 7;
      int kc = s ^ (row & 7);
      int gj = j0 + row; if (gj >= N) gj = N - 1;
      gload16(Bb + (long)gj * sBj + k0 + kc * 8, &Bs[chunk * 8]);
    }
    __syncthreads();
    #pragma unroll
    for (int ks = 0; ks < 2; ++ks) {
      short8 af[4], bfr[4];
      #pragma unroll
      for (int mi = 0; mi < 4; ++mi) {
        int row = wm * 64 + mi * 16 + col16;
        int slot = (ks * 4 + krow) ^ (row & 7);
        af[mi] = *(const short8*)&As[row * 64 + slot * 8];
      }
      #pragma unroll
      for (int nj = 0; nj < 4; ++nj) {
        int row = wn * 64 + nj * 16 + col16;
        int slot = (ks * 4 + krow) ^ (row & 7);
        bfr[nj] = *(const short8*)&Bs[row * 64 + slot * 8];
      }
      #pragma unroll
      for (int mi = 0; mi < 4; ++mi)
        #pragma unroll
        for (int nj = 0; nj < 4; ++nj)
          acc[mi][nj] = __builtin_amdgcn_mfma_f32_16x16x32_bf16(
              af[mi], bfr[nj], acc[mi][nj], 0, 0, 0);
    }
    __syncthreads();
  }

  const int r0 = (lane >> 4) * 4;
  #pragma unroll
  for (int mi = 0; mi < 4; ++mi) {
    int gi0 = i0 + wm * 64 + mi * 16 + r0;
    #pragma unroll
    for (int nj = 0; nj < 4; ++nj) {
      int gj = j0 + wn * 64 + nj * 16 + col16;
      f32x4 a = acc[mi][nj];
      #pragma unroll
      for (int r = 0; r < 4; ++r) {
        int gi = gi0 + r;
        if (gi >= M || gj >= N) continue;
        long ci = bCs * bz + (long)gi * sCi + gj;
        float v = a[r];
        if (mode == 0) v += (bias ? bias[gj] : 0.f);
        else v += bias[gi];
        ((float*)C)[ci] = v;
      }
    }
  }
}

// ---------------- bf16 MFMA GEMM, 64 x 208 full-N tile, 2-phase prefetch -----
// One block owns M-tile of 64 rows x ALL 208 cols (N<=208). BK=32, dbuf LDS.
// mode 1: bf16 out + bias[row]; cols [N,208) -> 0 and cols [208,224) -> 0
// mode 3: f32 out, gamma[0]*acc + resid[same index]
// Grid: 1D, mtiles * batches blocks; batch->XCD swizzle when batches%8==0.
__global__ __launch_bounds__(256) void vout_gemm(
    const ushort* __restrict__ A, const ushort* __restrict__ Bm,
    const float* __restrict__ bias, const float* __restrict__ resid,
    const float* __restrict__ gammaPtr, void* __restrict__ C,
    int N, int K,
    long sAi, long bAs, long sBj, long bBs,
    long sCi, long bCs, int mtiles, int batches, int mode)
{
  __shared__ ushort As[2][64 * 32];
  __shared__ ushort Bs[2][208 * 32];
  int bid = blockIdx.x;
  int mtile, bz;
  if ((batches & 7) == 0) {
    int xcd = bid & 7, s = bid >> 3;
    mtile = s % mtiles;
    bz = (s / mtiles) * 8 + xcd;
  } else {
    mtile = bid % mtiles;
    bz = bid / mtiles;
  }
  const ushort* Ab = A + bAs * bz + (long)(mtile * 64) * sAi;
  const ushort* Bb = Bm + bBs * bz;
  const int tid = threadIdx.x, wave = tid >> 6, lane = tid & 63;

  f32x4 acc[13] = {};

  // stage one 32-k tile: A 64 rows (4 KB) + B 208 rows (13 KB), 17 x 1KB chunks
  auto stage = [&](int buf, int k0) {
    const int lrow = lane >> 2, s = lane & 3;
    #pragma unroll
    for (int c0 = 0; c0 < 5; ++c0) {
      int c = wave + c0 * 4;
      if (c >= 17) break;                        // wave-uniform
      if (c < 4) {
        int row = c * 16 + lrow;
        int kc = s ^ (row & 3);
        gload16(Ab + (long)row * sAi + k0 + kc * 8,
                (char*)(&As[buf][0]) + c * 1024 + lane * 16);
      } else {
        int row = (c - 4) * 16 + lrow;
        int gj = row < N ? row : N - 1;
        int kc = s ^ (row & 3);
        gload16(Bb + (long)gj * sBj + k0 + kc * 8,
                (char*)(&Bs[buf][0]) + (c - 4) * 1024 + lane * 16);
      }
    }
  };

  const int fr = lane & 15, kq = lane >> 4;
  const int nt = K >> 5;

  stage(0, 0);
  __syncthreads();
  for (int t = 0; t < nt; ++t) {
    int cur = t & 1;
    if (t + 1 < nt) stage(cur ^ 1, (t + 1) << 5);
    int arow = wave * 16 + fr;
    short8 af = *(const short8*)((const char*)(&As[cur][0]) +
                                 arow * 64 + ((kq ^ (arow & 3)) << 4));
    #pragma unroll
    for (int j = 0; j < 13; ++j) {
      int brow = j * 16 + fr;
      short8 bf = *(const short8*)((const char*)(&Bs[cur][0]) +
                                   brow * 64 + ((kq ^ (brow & 3)) << 4));
      acc[j] = __builtin_amdgcn_mfma_f32_16x16x32_bf16(af, bf, acc[j], 0, 0, 0);
    }
    __syncthreads();
  }

  const int r0 = (lane >> 4) << 2;
  const int gi0 = mtile * 64 + wave * 16 + r0;
  if (mode == 3) {
    const float g = gammaPtr[0];
    #pragma unroll
    for (int j = 0; j < 13; ++j) {
      int gj = j * 16 + fr;
      if (gj >= N) continue;
      #pragma unroll
      for (int r = 0; r < 4; ++r) {
        long ci = bCs * bz + (long)(gi0 + r) * sCi + gj;
        ((float*)C)[ci] = g * acc[j][r] + resid[ci];
      }
    }
  } else {
    #pragma unroll
    for (int j = 0; j < 13; ++j) {
      int gj = j * 16 + fr;
      #pragma unroll
      for (int r = 0; r < 4; ++r) {
        int gi = gi0 + r;
        ushort o = (gj < N) ? f2bf(acc[j][r] + bias[gi]) : (ushort)0;
        ((ushort*)C)[bCs * bz + (long)gi * sCi + gj] = o;
      }
    }
    // zero cols [208,224) so a consumer with K=224 never reads stale bits
    #pragma unroll
    for (int r = 0; r < 4; ++r) {
      int gi = gi0 + r;
      ((ushort*)C)[bCs * bz + (long)gi * sCi + 208 + fr] = 0;
    }
  }
}

// ---------------- small helpers ----------------------------------------------
__global__ void fuse_bias(const float* __restrict__ Wks, const float* __restrict__ bk,
                          const float* __restrict__ bks, float* __restrict__ bf) {
  int c = blockIdx.x * blockDim.x + threadIdx.x;
  if (c >= 96) return;
  float s = bks[c];
  for (int e = 0; e < 96; ++e) s += Wks[c * 96 + e] * bk[e];
  bf[c] = s;
}

__global__ __launch_bounds__(256) void conv_plain(const float* __restrict__ s,
                                                  ushort* __restrict__ d, long n) {
  long i = (long)blockIdx.x * blockDim.x + threadIdx.x;
  long stride = (long)gridDim.x * blockDim.x;
  for (; i < n; i += stride) d[i] = f2bf(s[i]);
}

__global__ __launch_bounds__(256) void conv_pad256(const float* __restrict__ s,
                                                   ushort* __restrict__ d,
                                                   int rows, int cols) {
  long i = (long)blockIdx.x * blockDim.x + threadIdx.x;
  long n = (long)rows * 256;
  long stride = (long)gridDim.x * blockDim.x;
  for (; i < n; i += stride) {
    int r = (int)(i >> 8), c = (int)(i & 255);
    d[i] = (c < cols) ? f2bf(s[(long)r * cols + c]) : (ushort)0;
  }
}

__global__ __launch_bounds__(256) void conv_bf16x8(const float* __restrict__ s,
                                                   ushort* __restrict__ d, long n8) {
  long i = (long)blockIdx.x * blockDim.x + threadIdx.x;
  long stride = (long)gridDim.x * blockDim.x;
  for (; i < n8; i += stride) {
    float4 a = ((const float4*)s)[2 * i];
    float4 b = ((const float4*)s)[2 * i + 1];
    ushort8 o;
    o[0] = f2bf(a.x); o[1] = f2bf(a.y); o[2] = f2bf(a.z); o[3] = f2bf(a.w);
    o[4] = f2bf(b.x); o[5] = f2bf(b.y); o[6] = f2bf(b.z); o[7] = f2bf(b.w);
    *(ushort8*)&d[i * 8] = o;
  }
}

// E [197][197] f32 -> Eb [197][256] bf16 (pad 0) and ETb [197][256] bf16 (pad 0)
__global__ __launch_bounds__(256) void convE(const float* __restrict__ E,
                                             ushort* __restrict__ Ebuf,
                                             ushort* __restrict__ ETbuf) {
  __shared__ float tile[32][33];
  int b = blockIdx.z;
  const float* Es = E + (long)b * 38809;
  ushort* eb = Ebuf + (long)b * 50432;
  ushort* et = ETbuf + (long)b * 50432;
  int l0 = blockIdx.y * 32, m0 = blockIdx.x * 32;
  int tx = threadIdx.x & 31, ty = threadIdx.x >> 5;
  for (int r = ty; r < 32; r += 8) {
    int l = l0 + r, m = m0 + tx;
    tile[r][tx] = (l < 197 && m < 197) ? Es[(long)l * 197 + m] : 0.f;
  }
  __syncthreads();
  for (int r = ty; r < 32; r += 8) {
    int l = l0 + r, m = m0 + tx;
    if (l < 197 && m < 256) eb[(long)l * 256 + m] = f2bf(tile[r][tx]);
  }
  for (int r = ty; r < 32; r += 8) {
    int m = m0 + r, l = l0 + tx;
    if (m < 197 && l < 256) et[(long)m * 256 + l] = f2bf(tile[tx][r]);
  }
}

// column softmax: t [197 rows][256 stride] f32 -> a bf16 same layout
__global__ __launch_bounds__(256) void softmax_cols(const float* __restrict__ t1,
                                                    const float* __restrict__ t2,
                                                    ushort* __restrict__ a1,
                                                    ushort* __restrict__ a2) {
  int bid = blockIdx.x;
  int b = bid >> 1;
  const float* t = (bid & 1) ? t2 : t1;
  ushort* a = (bid & 1) ? a2 : a1;
  t += (long)b * 50432;
  a += (long)b * 50432;
  int l = threadIdx.x;
  if (l >= 197) {
    for (int m = 0; m < 197; ++m) a[(long)m * 256 + l] = 0;
    return;
  }
  float mx = -INFINITY;
  for (int m = 0; m < 197; ++m) mx = fmaxf(mx, t[(long)m * 256 + l]);
  float s = 0.f;
  for (int m = 0; m < 197; ++m) s += __expf(t[(long)m * 256 + l] - mx);
  float inv = 1.f / s;
  for (int m = 0; m < 197; ++m)
    a[(long)m * 256 + l] = f2bf(__expf(t[(long)m * 256 + l] - mx) * inv);
}

// ---------------- launcher ---------------------------------------------------
extern "C" void kernel_launch(void* const* d_in, const int* in_sizes, int n_in,
                              void* d_out, int out_size, void* d_ws, size_t ws_size,
                              hipStream_t stream) {
  const float* x   = (const float*)d_in[0];
  const float* y   = (const float*)d_in[1];
  const float* Wk1 = (const float*)d_in[2];
  const float* bk1 = (const float*)d_in[3];
  const float* Wk2 = (const float*)d_in[4];
  const float* bk2 = (const float*)d_in[5];
  const float* Wks = (const float*)d_in[6];
  const float* bks = (const float*)d_in[7];
  const float* Wl1 = (const float*)d_in[8];
  const float* bl1 = (const float*)d_in[9];
  const float* Wl2 = (const float*)d_in[10];
  const float* bl2 = (const float*)d_in[11];
  const float* Wv1 = (const float*)d_in[12];
  const float* bv1 = (const float*)d_in[13];
  const float* Wv2 = (const float*)d_in[14];
  const float* bv2 = (const float*)d_in[15];
  const float* gamma1 = (const float*)d_in[16];
  const float* gamma2 = (const float*)d_in[17];
  float* out = (float*)d_out;

  const int B = 256, L = 197, D = 768;
  const long LD  = (long)L * D;
  const long LDK = (long)L * 96;

  const size_t staticBytes = 589824 + 1024 + 2359296 + 294912 + 201728;
  const size_t perB = 605184 + 151296 + 155264 + 201728 + 403456 + 201728 + 393216;
  int Bc = 256;
  while (Bc > 4 && staticBytes + (size_t)Bc * perB > ws_size) Bc >>= 1;

  char* p = (char*)d_ws;
  auto carve = [&](size_t bytes) { char* r = p; p += bytes; return r; };
  float*  Wf1   = (float*)carve(73728 * 4);
  float*  Wf2   = (float*)carve(73728 * 4);
  float*  bf1   = (float*)carve(512);
  float*  bf2   = (float*)carve(512);
  ushort* Wv1b  = (ushort*)carve(589824 * 2);
  ushort* Wv2b  = (ushort*)carve(589824 * 2);
  ushort* Wf1b  = (ushort*)carve(73728 * 2);
  ushort* Wf2b  = (ushort*)carve(73728 * 2);
  ushort* Wl1b  = (ushort*)carve(50432 * 2);
  ushort* Wl2b  = (ushort*)carve(50432 * 2);
  ushort* xb    = (ushort*)carve((size_t)Bc * LD * 2);
  ushort* yb    = (ushort*)carve((size_t)Bc * LD * 2);
  float*  k1    = (float*)carve((size_t)Bc * LDK * 4);
  float*  k2    = (float*)carve((size_t)Bc * LDK * 4);
  float*  E     = (float*)carve((size_t)Bc * 155264);
  ushort* Ebuf  = (ushort*)carve((size_t)Bc * 50432 * 2);
  ushort* ETbuf = (ushort*)carve((size_t)Bc * 50432 * 2);
  float*  t1    = (float*)carve((size_t)Bc * 50432 * 4);
  float*  t2    = (float*)carve((size_t)Bc * 50432 * 4);
  ushort* a1    = (ushort*)carve((size_t)Bc * 50432 * 2);
  ushort* a2    = (ushort*)carve((size_t)Bc * 50432 * 2);
  ushort* vT    = (ushort*)carve((size_t)Bc * 196608 * 2);

  dim3 blk(256);

  gemm_generic<<<dim3(12, 2, 1), blk, 0, stream>>>(Wks, Wk1, Wf1,
      96, 768, 96, 96, 1, 0, 1, 768, 0, 768, 0);
  gemm_generic<<<dim3(12, 2, 1), blk, 0, stream>>>(Wks, Wk2, Wf2,
      96, 768, 96, 96, 1, 0, 1, 768, 0, 768, 0);
  fuse_bias<<<1, 128, 0, stream>>>(Wks, bk1, bks, bf1);
  fuse_bias<<<1, 128, 0, stream>>>(Wks, bk2, bks, bf2);
  conv_plain<<<dim3(72), blk, 0, stream>>>(Wf1, Wf1b, 73728);
  conv_plain<<<dim3(72), blk, 0, stream>>>(Wf2, Wf2b, 73728);
  conv_plain<<<dim3(576), blk, 0, stream>>>(Wv1, Wv1b, 589824);
  conv_plain<<<dim3(576), blk, 0, stream>>>(Wv2, Wv2b, 589824);
  conv_pad256<<<dim3(200), blk, 0, stream>>>(Wl1, Wl1b, 197, 197);
  conv_pad256<<<dim3(200), blk, 0, stream>>>(Wl2, Wl2b, 197, 197);

  for (int c0 = 0; c0 < B; c0 += Bc) {
    const float* xc = x + (long)c0 * LD;
    const float* yc = y + (long)c0 * LD;
    const int Mr = Bc * L;
    const int gym = (Mr + 127) / 128;

    conv_bf16x8<<<dim3(2048), blk, 0, stream>>>(xc, xb, (long)Bc * LD / 8);
    conv_bf16x8<<<dim3(2048), blk, 0, stream>>>(yc, yb, (long)Bc * LD / 8);

    // k1 = xb @ Wf1b^T + bf1 -> f32 [Mr][96]
    mfma_gemm<<<dim3(1, gym, 1), blk, 0, stream>>>(xb, Wf1b, bf1, k1,
        Mr, 96, 768, 768, 0, 768, 0, 96, 0, 0);
    mfma_gemm<<<dim3(1, gym, 1), blk, 0, stream>>>(yb, Wf2b, bf2, k2,
        Mr, 96, 768, 768, 0, 768, 0, 96, 0, 0);

    // energy (fp32 VALU): E[b][l][m] = sum_c k1f[c*197+l] * k2f[c*197+m]
    gemm_generic<<<dim3(4, 4, Bc), blk, 0, stream>>>(k1, k2, E,
        197, 197, 96, 1, 197, LDK, 1, 197, LDK, 197, 38809);

    convE<<<dim3(8, 8, Bc), blk, 0, stream>>>(E, Ebuf, ETbuf);

    // t1[m][l] = sum_m' Wl1[m][m'] * E[l][m'] + bl1[m]
    mfma_gemm<<<dim3(2, 2, Bc), blk, 0, stream>>>(Wl1b, Ebuf, bl1, t1,
        197, 197, 256, 256, 0, 256, 50432, 256, 50432, 2);
    mfma_gemm<<<dim3(2, 2, Bc), blk, 0, stream>>>(Wl2b, ETbuf, bl2, t2,
        197, 197, 256, 256, 0, 256, 50432, 256, 50432, 2);

    softmax_cols<<<dim3(2 * Bc), blk, 0, stream>>>(t1, t2, a1, a2);

    // vT[b][d][l] = sum_e Wv2[d][e]*y[b][l][e] + bv2[d], bf16, cols 197..223 = 0
    vout_gemm<<<dim3(12 * Bc), blk, 0, stream>>>(Wv2b, yb, bv2, nullptr, nullptr, vT,
        197, 768, 768, 0, 768, LD, 256, 196608, 12, Bc, 1);
    // out_x[b][d][m] = gamma1 * sum_l vT[d][l]*a1[m][l] + x.flat
    vout_gemm<<<dim3(12 * Bc), blk, 0, stream>>>(vT, a1, nullptr, xc, gamma1,
        out + (long)c0 * LD,
        197, 224, 256, 196608, 256, 50432, 197, LD, 12, Bc, 3);

    vout_gemm<<<dim3(12 * Bc), blk, 0, stream>>>(Wv1b, xb, bv1, nullptr, nullptr, vT,
        197, 768, 768, 0, 768, LD, 256, 196608, 12, Bc, 1);
    vout_gemm<<<dim3(12 * Bc), blk, 0, stream>>>(vT, a2, nullptr, yc, gamma2,
        out + (long)B * LD + (long)c0 * LD,
        197, 224, 256, 196608, 256, 50432, 197, LD, 12, Bc, 3);
  }
}